// Round 2
// baseline (551.686 us; speedup 1.0000x reference)
//
#include <hip/hip_runtime.h>
#include <math.h>

// out_b = E * x_b * E^T per batch, E = D@D, D[k][j] = 2 cos(pi*k*(2j+1)/512).
// Fully fused, quarter-granular: block = (batch, row-quarter q). Phase 1
// computes W_q = E[q*64:+64,:] @ x_b into 32 KiB LDS (bf16, XOR-swizzled);
// phase 2 computes out rows [q*64,+64) = W_q @ E^T. 48 KiB LDS/block ->
// 3 independent blocks/CU (12 waves) to hide latency.

typedef __bf16 bf16x8 __attribute__((ext_vector_type(8)));
typedef float f32x4 __attribute__((ext_vector_type(4)));
typedef unsigned int u32x2 __attribute__((ext_vector_type(2)));
typedef unsigned int u32x4 __attribute__((ext_vector_type(4)));

__device__ __forceinline__ unsigned short f2bf(float f) {
  unsigned u = __builtin_bit_cast(unsigned, f);
  u += 0x7fffu + ((u >> 16) & 1u);  // round-to-nearest-even (finite inputs)
  return (unsigned short)(u >> 16);
}

__device__ __forceinline__ unsigned pack2(float a, float b) {
  return (unsigned)f2bf(a) | ((unsigned)f2bf(b) << 16);
}

// D[i][j] = 2 cos(pi * i * (2j+1) / 512); exact integer angle reduction mod 1024.
__global__ void k_dmat(float* __restrict__ D) {
  const int i = blockIdx.x, j = threadIdx.x;
  const int m = (i * (2 * j + 1)) & 1023;
  D[(i << 8) + j] = 2.0f * cosf((float)m * 6.135923151542565e-3f);  // pi/512
}

// E = D @ D, stored as bf16 bits (row-major 256x256).
__global__ void k_emat(const float* __restrict__ D, unsigned short* __restrict__ E) {
  const int i = blockIdx.x, j = threadIdx.x;
  const float* Di = D + (i << 8);
  float acc = 0.0f;
  for (int m = 0; m < 256; ++m) acc = fmaf(Di[m], D[(m << 8) + j], acc);
  E[(i << 8) + j] = f2bf(acc);
}

__global__ __launch_bounds__(256, 3) void k_fused(
    const unsigned short* __restrict__ E, const float* __restrict__ X,
    float* __restrict__ OUT) {
  __shared__ __align__(16) unsigned short Wl[64 * 256];  // 32 KiB, swizzled rows
  __shared__ __align__(16) unsigned short xb[32 * 256];  // 16 KiB, frag order

  const int phys = blockIdx.x;
  const int lb = ((phys & 7) << 9) + (phys >> 3);  // XCD-chunked (4096 % 8 == 0)
  const int batch = lb >> 2, h = lb & 3;           // row-quarter h
  const int t = threadIdx.x;
  const int l = t & 63, w = t >> 6;  // w = wave = col-quarter (ph1/ph2) & k-octet (staging)
  const int lr = l & 15, lq = l >> 4;

  // x staging: wave w loads k-rows w*8+i of the strip; lane l loads cols l*4..+3
  const float* Xb = X + ((size_t)batch << 16) + (w << 11) + (l << 2);
  // E fragment bases (global; E is 128 KiB, L2-hot)
  const unsigned short* Ep1 = E + (((h << 6) + lr) << 8) + (lq << 3);  // W rows
  const unsigned short* Ep2 = E + (((w << 6) + lr) << 8) + (lq << 3);  // out cols

  f32x4 acc[4][4];
#pragma unroll
  for (int a = 0; a < 4; ++a)
#pragma unroll
    for (int c = 0; c < 4; ++c)
#pragma unroll
      for (int e = 0; e < 4; ++e) acc[a][c][e] = 0.0f;

  // ---------------- phase 1: W_q = E_q * x_b (computed as W^T tiles) -------
  f32x4 xv[2][8];
#pragma unroll
  for (int i = 0; i < 8; ++i) xv[0][i] = *(const f32x4*)(Xb + (i << 8));

#pragma unroll
  for (int kt = 0; kt < 8; ++kt) {
    const int cur = kt & 1;
    if (kt) {  // previous strip's reads complete at each wave's barrier
      asm volatile("" ::: "memory");
      __builtin_amdgcn_s_barrier();
      asm volatile("" ::: "memory");
    }
    // pack fp32 -> bf16 k-pairs, write in MFMA fragment order, XOR-swizzled
    const int fr = l >> 2;  // col-tile this thread feeds
#pragma unroll
    for (int c = 0; c < 4; ++c) {
      u32x4 p;
      p.x = pack2(xv[cur][0][c], xv[cur][1][c]);
      p.y = pack2(xv[cur][2][c], xv[cur][3][c]);
      p.z = pack2(xv[cur][4][c], xv[cur][5][c]);
      p.w = pack2(xv[cur][6][c], xv[cur][7][c]);
      const int lane = (w << 4) + ((l & 3) << 2) + c;
      ((u32x4*)xb)[(fr << 6) + (lane ^ (fr & 7))] = p;
    }
    // T14: issue next strip's global loads before the barrier stall
    if (kt < 7) {
      const float* xg = Xb + ((kt + 1) << 13);
#pragma unroll
      for (int i = 0; i < 8; ++i) xv[cur ^ 1][i] = *(const f32x4*)(xg + (i << 8));
    }
    asm volatile("s_waitcnt lgkmcnt(0)" ::: "memory");  // own ds_writes done
    __builtin_amdgcn_s_barrier();                       // no vmcnt drain!
    asm volatile("" ::: "memory");

    bf16x8 bx[4], ef[4];
#pragma unroll
    for (int tc = 0; tc < 4; ++tc) {
      const int f = (w << 2) + tc;
      bx[tc] = ((const bf16x8*)xb)[(f << 6) + (l ^ (f & 7))];
    }
#pragma unroll
    for (int tm = 0; tm < 4; ++tm)
      ef[tm] = *(const bf16x8*)(Ep1 + (tm << 12) + (kt << 5));
    // swapped operands: A = x^T frag, B = E frag  ->  D = W^T tile
#pragma unroll
    for (int tm = 0; tm < 4; ++tm)
#pragma unroll
      for (int tc = 0; tc < 4; ++tc)
        acc[tm][tc] = __builtin_amdgcn_mfma_f32_16x16x32_bf16(
            bx[tc], ef[tm], acc[tm][tc], 0, 0, 0);
  }

  // W epilogue: lane holds W[tm*16+lr][w*64+tc*16+lq*4 + r], r=0..3
  // -> packed 8B LDS writes, XOR-swizzled rows (stride 512 B).
#pragma unroll
  for (int tm = 0; tm < 4; ++tm) {
    const int row = (tm << 4) + lr;
    char* rowp = (char*)Wl + (row << 9);
    const int swz = (lr & 7) << 4;
#pragma unroll
    for (int tc = 0; tc < 4; ++tc) {
      u32x2 pw;
      pw.x = pack2(acc[tm][tc][0], acc[tm][tc][1]);
      pw.y = pack2(acc[tm][tc][2], acc[tm][tc][3]);
      const int coff = (w << 7) + (tc << 5) + (lq << 3);
      *(u32x2*)(rowp + (coff ^ swz)) = pw;
    }
  }
  asm volatile("s_waitcnt lgkmcnt(0)" ::: "memory");
  __builtin_amdgcn_s_barrier();
  asm volatile("" ::: "memory");

  // ---------------- phase 2: out_q = W_q * E^T (computed as out^T tiles) ---
#pragma unroll
  for (int a = 0; a < 4; ++a)
#pragma unroll
    for (int c = 0; c < 4; ++c)
#pragma unroll
      for (int e = 0; e < 4; ++e) acc[a][c][e] = 0.0f;

#pragma unroll
  for (int kk = 0; kk < 8; ++kk) {
    bf16x8 wf[4], ef[4];
#pragma unroll
    for (int tm = 0; tm < 4; ++tm) {
      const int row = (tm << 4) + lr;
      const int koff = (kk << 6) + (lq << 4);
      wf[tm] = *(const bf16x8*)((const char*)Wl + (row << 9) +
                                (koff ^ ((lr & 7) << 4)));
    }
#pragma unroll
    for (int tn = 0; tn < 4; ++tn)
      ef[tn] = *(const bf16x8*)(Ep2 + (tn << 12) + (kk << 5));
    // swapped operands: A = E frag (out cols), B = W frag -> D = out^T tile
#pragma unroll
    for (int tm = 0; tm < 4; ++tm)
#pragma unroll
      for (int tn = 0; tn < 4; ++tn)
        acc[tm][tn] = __builtin_amdgcn_mfma_f32_16x16x32_bf16(
            ef[tn], wf[tm], acc[tm][tn], 0, 0, 0);
  }

  // lane holds out[h*64+tm*16+lr][w*64+tn*16+lq*4 + r] -> dwordx4 stores
  float* Ob = OUT + ((size_t)batch << 16) + (h << 14);
#pragma unroll
  for (int tm = 0; tm < 4; ++tm) {
    float* rowp = Ob + (((tm << 4) + lr) << 8) + (w << 6) + (lq << 2);
#pragma unroll
    for (int tn = 0; tn < 4; ++tn)
      *(f32x4*)(rowp + (tn << 4)) = acc[tm][tn];
  }
}

extern "C" void kernel_launch(void* const* d_in, const int* in_sizes, int n_in,
                              void* d_out, int out_size, void* d_ws, size_t ws_size,
                              hipStream_t stream) {
  (void)in_sizes; (void)n_in; (void)out_size; (void)ws_size;
  const float* X = (const float*)d_in[0];
  float* OUT = (float*)d_out;
  char* ws = (char*)d_ws;
  float* D = (float*)ws;                                    // 256 KiB
  unsigned short* E = (unsigned short*)(ws + (256 * 1024)); // 128 KiB

  k_dmat<<<dim3(256), dim3(256), 0, stream>>>(D);
  k_emat<<<dim3(256), dim3(256), 0, stream>>>(D, E);
  k_fused<<<dim3(4096), dim3(256), 0, stream>>>(E, X, OUT);
}